// Round 2
// baseline (451.312 us; speedup 1.0000x reference)
//
#include <hip/hip_runtime.h>

#define T_DIM 2048
#define D_DIM 256
#define K_CODES 512
#define B_DIM 64
#define N_ROWS (B_DIM * T_DIM)           // 131072
#define Q_ELEMS (B_DIM * D_DIM * T_DIM)  // 33554432

#define TN 128  // t-rows per block
#define TK 128  // codes per chunk
#define DC 64   // d per LDS stage

#define GATHER_BLOCKS 8192

// ws layout:
// [0, 2048)            norms (512 f32)  -- numpy-pairwise-exact ||e_k||^2
// [2048, 67584)        blockSums (8192 f64)
// [67584, 591872)      eT (256 x 512 f32), only if ws_size >= 591872

__device__ __forceinline__ float comb8(const float r[8]) {
  return ((r[0] + r[1]) + (r[2] + r[3])) + ((r[4] + r[5]) + (r[6] + r[7]));
}

// One block per code k: stage row, emit transpose, thread 0 replicates
// numpy pairwise_sum(fl(e*e)) exactly: 256 -> two 128-blocks (8-acc unroll),
// res = block0 + block1.
__global__ __launch_bounds__(256) void vq_prep(const float* __restrict__ e,
                                               float* __restrict__ norms,
                                               float* __restrict__ eT, int use_eT) {
  __shared__ float srow[D_DIM];
  int k = blockIdx.x;
  int t = threadIdx.x;
  float v = e[k * D_DIM + t];
  srow[t] = v;
  if (use_eT) eT[(size_t)t * K_CODES + k] = v;
  __syncthreads();
  if (t == 0) {
    float res[2];
    #pragma unroll
    for (int blk2 = 0; blk2 < 2; ++blk2) {
      float r[8];
      #pragma unroll
      for (int j = 0; j < 8; ++j) {
        float a = srow[blk2 * 128 + j];
        r[j] = __fmul_rn(a, a);              // square rounded, no fma
      }
      for (int i = 8; i < 128; i += 8)
        #pragma unroll
        for (int j = 0; j < 8; ++j) {
          float a = srow[blk2 * 128 + i + j];
          r[j] = __fadd_rn(r[j], __fmul_rn(a, a));
        }
      res[blk2] = comb8(r);
    }
    norms[k] = __fadd_rn(res[0], res[1]);
  }
}

__global__ __launch_bounds__(256, 2) void vq_main(
    const float* __restrict__ x, const float* __restrict__ e,
    const float* __restrict__ norms, const float* __restrict__ eT,
    float* __restrict__ out_idx, int use_eT) {
  __shared__ float xs[DC][TN + 4];   // 33792 B
  __shared__ float es[DC][TK + 4];   // 33792 B
  __shared__ float nlds[K_CODES];    // 2048 B
  __shared__ float xxs[TN];          // 512 B  (numpy-pairwise ||x_row||^2)

  const int tx = threadIdx.x;
  const int blk = blockIdx.x;          // 1024 blocks
  const int b = blk >> 4;
  const int t0 = (blk & 15) * TN;

  nlds[tx] = norms[tx];
  nlds[tx + 256] = norms[tx + 256];

  const int r = tx & 15;   // rows 8r..8r+7
  const int c = tx >> 4;   // cols 8c..8c+7

  float runmin[8];
  int runidx[8];
  #pragma unroll
  for (int i = 0; i < 8; ++i) { runmin[i] = 3.4e38f; runidx[i] = 0; }

  const float* xbase = x + (size_t)b * (D_DIM * T_DIM) + t0;
  const int f4 = tx & 31;
  const int dr = tx >> 5;

  // numpy-pairwise state for xx (threads 0..127, one row each, kc==0 only)
  float r8[8];
  float xpart = 0.f;
  #pragma unroll
  for (int j = 0; j < 8; ++j) r8[j] = 0.f;

  for (int kc = 0; kc < 4; ++kc) {
    float acc[8][8];
    #pragma unroll
    for (int i = 0; i < 8; ++i)
      #pragma unroll
      for (int j = 0; j < 8; ++j) acc[i][j] = 0.f;

    for (int dc = 0; dc < 4; ++dc) {
      __syncthreads();
      #pragma unroll
      for (int p = 0; p < 8; ++p) {
        int dd = p * 8 + dr;
        float4 v = *(const float4*)(xbase + (size_t)(dc * DC + dd) * T_DIM + f4 * 4);
        *(float4*)&xs[dd][f4 * 4] = v;
      }
      if (use_eT) {
        #pragma unroll
        for (int p = 0; p < 8; ++p) {
          int dd = p * 8 + dr;
          float4 v = *(const float4*)(eT + (size_t)(dc * DC + dd) * K_CODES + kc * TK + f4 * 4);
          *(float4*)&es[dd][f4 * 4] = v;
        }
      } else {
        int kkb = tx & 63;
        int qb = tx >> 6;
        #pragma unroll
        for (int p = 0; p < 8; ++p) {
          int kk = kkb + 64 * (p & 1);
          int q = qb + 4 * (p >> 1);
          float4 v = *(const float4*)(e + (size_t)(kc * TK + kk) * D_DIM + dc * DC + q * 4);
          es[q * 4 + 0][kk] = v.x;
          es[q * 4 + 1][kk] = v.y;
          es[q * 4 + 2][kk] = v.z;
          es[q * 4 + 3][kk] = v.w;
        }
      }
      __syncthreads();

      // xx accumulation (exact numpy pairwise: ascending d, acc index d&7,
      // squares rounded before add)
      if (kc == 0 && tx < TN) {
        for (int dd = 0; dd < DC; ++dd) {
          float v = xs[dd][tx];
          r8[dd & 7] = __fadd_rn(r8[dd & 7], __fmul_rn(v, v));
        }
        if (dc == 1) {
          xpart = comb8(r8);
          #pragma unroll
          for (int j = 0; j < 8; ++j) r8[j] = 0.f;
        } else if (dc == 3) {
          xxs[tx] = __fadd_rn(xpart, comb8(r8));
        }
      }

      // m_k: strict sequential-k fp32 fma (d ascending across dc chunks)
      #pragma unroll 2
      for (int dd = 0; dd < DC; ++dd) {
        float xr[8], er[8];
        *(float4*)&xr[0] = *(const float4*)&xs[dd][8 * r];
        *(float4*)&xr[4] = *(const float4*)&xs[dd][8 * r + 4];
        *(float4*)&er[0] = *(const float4*)&es[dd][8 * c];
        *(float4*)&er[4] = *(const float4*)&es[dd][8 * c + 4];
        #pragma unroll
        for (int i = 0; i < 8; ++i)
          #pragma unroll
          for (int j = 0; j < 8; ++j)
            acc[i][j] = __fmaf_rn(xr[i], er[j], acc[i][j]);
      }
    }

    __syncthreads();  // xxs ready (kc==0); also guards LDS reuse timing
    // dist_k = fl(fl(xx + ee_k) - 2*m_k), replicating the reference's fp32
    // quantization; strict < + ascending k == first-index tie-break.
    #pragma unroll
    for (int i = 0; i < 8; ++i) {
      float xxr = xxs[8 * r + i];
      #pragma unroll
      for (int j = 0; j < 8; ++j) {
        int kidx = kc * TK + 8 * c + j;
        float t1 = __fadd_rn(xxr, nlds[kidx]);
        float s = t1 - 2.0f * acc[i][j];   // fma(-2,acc,t1) bit-equal: 2*acc exact
        if (s < runmin[i]) { runmin[i] = s; runidx[i] = kidx; }
      }
    }
  }

  // cross-thread argmin reduce (16 col-groups per row), ties -> lowest index
  __syncthreads();
  float* redm = (float*)xs;
  int*   redi = (int*)es;
  #pragma unroll
  for (int i = 0; i < 8; ++i) {
    int row = 8 * r + i;
    redm[row * 16 + c] = runmin[i];
    redi[row * 16 + c] = runidx[i];
  }
  __syncthreads();
  if (tx < TN) {
    float m = redm[tx * 16];
    int mi = redi[tx * 16];
    #pragma unroll
    for (int g = 1; g < 16; ++g) {
      float s2 = redm[tx * 16 + g];
      int si = redi[tx * 16 + g];
      if (s2 < m || (s2 == m && si < mi)) { m = s2; mi = si; }
    }
    out_idx[b * T_DIM + t0 + tx] = (float)mi;
  }
}

// Faithful view/permute quirk: q_out flat buffer == gathered [N,D] flat buffer,
// so each 256-aligned chunk m>>8 is the full row e[idx[m>>8], :].
__global__ __launch_bounds__(256) void vq_gather(const float* __restrict__ x,
                                                 const float* __restrict__ e,
                                                 const float* __restrict__ idxf,
                                                 float* __restrict__ out_q,
                                                 double* __restrict__ bsums) {
  __shared__ double sred[4];
  int tid = blockIdx.x * 256 + threadIdx.x;
  float lsum = 0.f;
  #pragma unroll
  for (int p = 0; p < 4; ++p) {
    int g = tid + p * (GATHER_BLOCKS * 256);   // float4 index
    int n = g >> 6;                            // row of [N, D] view
    int kk = (int)idxf[n];
    float4 ev = ((const float4*)e)[kk * 64 + (g & 63)];
    float4 xv = ((const float4*)x)[g];
    ((float4*)out_q)[g] = ev;
    float d0 = ev.x - xv.x, d1 = ev.y - xv.y, d2 = ev.z - xv.z, d3 = ev.w - xv.w;
    lsum += d0 * d0 + d1 * d1 + d2 * d2 + d3 * d3;
  }
  double ds = (double)lsum;
  #pragma unroll
  for (int o = 32; o > 0; o >>= 1) ds += __shfl_down(ds, o, 64);
  if ((threadIdx.x & 63) == 0) sred[threadIdx.x >> 6] = ds;
  __syncthreads();
  if (threadIdx.x == 0)
    bsums[blockIdx.x] = (sred[0] + sred[1]) + (sred[2] + sred[3]);
}

__global__ __launch_bounds__(256) void vq_final(const double* __restrict__ bs,
                                                float* __restrict__ out_loss) {
  __shared__ double sred[4];
  int t = threadIdx.x;
  double s = 0.0;
  for (int i = t; i < GATHER_BLOCKS; i += 256) s += bs[i];
  #pragma unroll
  for (int o = 32; o > 0; o >>= 1) s += __shfl_down(s, o, 64);
  if ((t & 63) == 0) sred[t >> 6] = s;
  __syncthreads();
  if (t == 0)
    out_loss[0] = (float)(0.25 * (((sred[0] + sred[1]) + (sred[2] + sred[3])) /
                                  (double)Q_ELEMS));
}

extern "C" void kernel_launch(void* const* d_in, const int* in_sizes, int n_in,
                              void* d_out, int out_size, void* d_ws, size_t ws_size,
                              hipStream_t stream) {
  const float* x = (const float*)d_in[0];
  const float* e = (const float*)d_in[1];
  float* out = (float*)d_out;
  float* out_q = out;
  float* out_loss = out + Q_ELEMS;
  float* out_idx = out + Q_ELEMS + 1;

  char* ws = (char*)d_ws;
  float* norms = (float*)ws;
  double* bsums = (double*)(ws + 2048);
  float* eT = (float*)(ws + 67584);
  int use_eT = (ws_size >= 591872) ? 1 : 0;

  vq_prep<<<K_CODES, 256, 0, stream>>>(e, norms, eT, use_eT);
  vq_main<<<N_ROWS / TN, 256, 0, stream>>>(x, e, norms, eT, out_idx, use_eT);
  vq_gather<<<GATHER_BLOCKS, 256, 0, stream>>>(x, e, out_idx, out_q, bsums);
  vq_final<<<1, 256, 0, stream>>>(bsums, out_loss);
}